// Round 1
// baseline (571.478 us; speedup 1.0000x reference)
//
#include <hip/hip_runtime.h>
#include <hip/hip_bf16.h>

// MFBasedModel fused kernel, round 1 (correctness-first f32).
// B=16384 rows; per row: 2 gumbel-routed top-8 passes over 2048 experts + MLP mixture.
// One block = 16 rows (32 row-tasks: row x {tgt,src}). C staged in LDS in 128-cand
// chunks; 4x4 per-thread f32 register tile for S = p @ C^T; online softmax + online
// top-8 per thread (8 threads per row-task), shuffle merge; fused MLP epilogue.

#define BROWS 16384
#define CNUM  2048
#define KSEL  8
#define DIMD  10
#define MDIM  50
#define RPB   16
#define RTPB  32
#define CH    128
#define NCH   (CNUM/CH)
#define KP    52      // padded K stride (floats), zero-padded cols 50..51
#define LSTR  132     // l-buffer row stride (floats)

typedef float f4 __attribute__((ext_vector_type(4)));

__global__ __launch_bounds__(256, 3)
void mf_fused(const int* __restrict__ x32,
              const float* __restrict__ gsrc,
              const float* __restrict__ gtgt,
              const float* __restrict__ suid,
              const float* __restrict__ tuid,
              const float* __restrict__ tiid,
              const float* __restrict__ Cm,
              const float* __restrict__ w1,
              const float* __restrict__ w2,
              const float* __restrict__ mw1,
              const float* __restrict__ mb1,
              const float* __restrict__ mw2,
              const float* __restrict__ mb2,
              float* __restrict__ out)
{
    __shared__ __align__(16) float sm[12544];
    __shared__ float sTopW[RTPB*KSEL];
    __shared__ int   sTopI[RTPB*KSEL];
    __shared__ int   sFlag;

    float* sC = sm;                     // [CH][KP]    6656 floats
    float* sP = sm + CH*KP;             // [RTPB][KP]  1664 floats
    float* sL = sm + CH*KP + RTPB*KP;   // [RTPB][LSTR] 4224 floats

    const int tid  = threadIdx.x;
    const int row0 = blockIdx.x * RPB;

    // ---- detect x dtype: int64 (all odd int32 words zero) vs int32 ----
    if (tid == 0) sFlag = 1;
    __syncthreads();
    if (tid < 128) { if (x32[2*tid+1] != 0) atomicAnd(&sFlag, 0); }
    __syncthreads();
    const int is64 = sFlag;

    // ---- p = emb @ w1 for 32 row-tasks (rt = 2*r_local + route; 0=tgt,1=src) ----
    for (int t = tid; t < RTPB*KP; t += 256) {
        const int rt = t / KP, mm = t - rt*KP;
        float v = 0.f;
        if (mm < MDIM) {
            const int r = row0 + (rt >> 1);
            const int uidx = is64 ? x32[4*r] : x32[2*r];
            const float* tab = (rt & 1) ? suid : tuid;
            #pragma unroll
            for (int d = 0; d < DIMD; ++d)
                v += tab[uidx*DIMD + d] * w1[d*MDIM + mm];
        }
        sP[t] = v;
    }

    // ---- per-thread online routing state: rtB = tid>>3 owns 256 candidates ----
    float tm = -3.4e38f, ts = 0.f;
    float tv0=-3.4e38f,tv1=-3.4e38f,tv2=-3.4e38f,tv3=-3.4e38f,
          tv4=-3.4e38f,tv5=-3.4e38f,tv6=-3.4e38f,tv7=-3.4e38f;
    int   ti0=0,ti1=0,ti2=0,ti3=0,ti4=0,ti5=0,ti6=0,ti7=0;

    const int cg = tid & 31, rg = tid >> 5;   // phase A: 4 cands (cg+32i) x 4 rts (rg*4+ii)
    const int rtB = tid >> 3, li = tid & 7;   // phase B: 8 lanes per row-task

    for (int ch = 0; ch < NCH; ++ch) {
        const int c0 = ch * CH;
        __syncthreads();
        // stage C chunk (zero-padded to KP)
        for (int t = tid; t < CH*KP; t += 256) {
            const int rr = t / KP, cc = t - rr*KP;
            sC[t] = (cc < MDIM) ? Cm[(c0+rr)*MDIM + cc] : 0.f;
        }
        __syncthreads();

        // ---- phase A: S tile + gumbel -> l values ----
        float uu[4][4];
        #pragma unroll
        for (int ii = 0; ii < 4; ++ii) {
            const int rt = rg*4 + ii;
            const float* gu = (rt & 1) ? gsrc : gtgt;
            const int r = row0 + (rt >> 1);
            #pragma unroll
            for (int i = 0; i < 4; ++i)
                uu[ii][i] = gu[r*CNUM + c0 + cg + 32*i];
        }
        float acc[4][4];
        #pragma unroll
        for (int i = 0; i < 4; ++i)
            #pragma unroll
            for (int ii = 0; ii < 4; ++ii) acc[i][ii] = 0.f;

        const f4* sC4 = (const f4*)sC;
        const f4* sP4 = (const f4*)sP;
        #pragma unroll
        for (int mg = 0; mg < KP/4; ++mg) {
            f4 cv[4], pv[4];
            #pragma unroll
            for (int i = 0; i < 4; ++i)  cv[i]  = sC4[(cg + 32*i)*(KP/4) + mg];
            #pragma unroll
            for (int ii = 0; ii < 4; ++ii) pv[ii] = sP4[(rg*4 + ii)*(KP/4) + mg];
            #pragma unroll
            for (int i = 0; i < 4; ++i)
                #pragma unroll
                for (int ii = 0; ii < 4; ++ii)
                    acc[i][ii] += cv[i].x*pv[ii].x + cv[i].y*pv[ii].y
                                + cv[i].z*pv[ii].z + cv[i].w*pv[ii].w;
        }
        #pragma unroll
        for (int ii = 0; ii < 4; ++ii) {
            const int rt = rg*4 + ii;
            #pragma unroll
            for (int i = 0; i < 4; ++i) {
                const float gn = -__logf(-__logf(uu[ii][i] + 1e-20f) + 1e-20f);
                sL[rt*LSTR + cg + 32*i] = (acc[i][ii] + gn) * 0.1f;
            }
        }
        __syncthreads();

        // ---- phase B: online softmax + online top-8 ----
        const f4* sL4 = (const f4*)sL;
        f4 lv[4];
        #pragma unroll
        for (int j = 0; j < 4; ++j) lv[j] = sL4[rtB*(LSTR/4) + li*4 + j];
        float lmax = lv[0].x;
        #pragma unroll
        for (int j = 0; j < 4; ++j)
            lmax = fmaxf(lmax, fmaxf(fmaxf(lv[j].x, lv[j].y), fmaxf(lv[j].z, lv[j].w)));
        const float nm = fmaxf(tm, lmax);
        ts *= __expf(tm - nm);
        tm = nm;
        #pragma unroll
        for (int j = 0; j < 4; ++j) {
            #pragma unroll
            for (int t = 0; t < 4; ++t) {
                const float l = (t==0)?lv[j].x:(t==1)?lv[j].y:(t==2)?lv[j].z:lv[j].w;
                const int gc = c0 + li*16 + 4*j + t;
                ts += __expf(l - tm);
                if (l > tv0) {
                    tv0 = l; ti0 = gc;
                    if (tv0 > tv1){float f=tv0;tv0=tv1;tv1=f;int q=ti0;ti0=ti1;ti1=q;}
                    if (tv1 > tv2){float f=tv1;tv1=tv2;tv2=f;int q=ti1;ti1=ti2;ti2=q;}
                    if (tv2 > tv3){float f=tv2;tv2=tv3;tv3=f;int q=ti2;ti2=ti3;ti3=q;}
                    if (tv3 > tv4){float f=tv3;tv3=tv4;tv4=f;int q=ti3;ti3=ti4;ti4=q;}
                    if (tv4 > tv5){float f=tv4;tv4=tv5;tv5=f;int q=ti4;ti4=ti5;ti5=q;}
                    if (tv5 > tv6){float f=tv5;tv5=tv6;tv6=f;int q=ti5;ti5=ti6;ti6=q;}
                    if (tv6 > tv7){float f=tv6;tv6=tv7;tv7=f;int q=ti6;ti6=ti7;ti7=q;}
                }
            }
        }
    }

    // ---- merge within 8-lane groups (one group per row-task) ----
    float m = tm;
    #pragma unroll
    for (int k = 1; k < 8; k <<= 1) m = fmaxf(m, __shfl_xor(m, k, 8));
    float s = ts * __expf(tm - m);
    #pragma unroll
    for (int k = 1; k < 8; k <<= 1) s += __shfl_xor(s, k, 8);
    const float invd = 1.0f / s;

    #pragma unroll
    for (int k = 0; k < KSEL; ++k) {
        float bv = tv7; int bi = ti7;
        #pragma unroll
        for (int mk = 1; mk < 8; mk <<= 1) {
            const float ov = __shfl_xor(bv, mk, 8);
            const int   oi = __shfl_xor(bi, mk, 8);
            if (ov > bv || (ov == bv && oi < bi)) { bv = ov; bi = oi; }
        }
        if (tv7 == bv && ti7 == bi) {   // unique pop (index uniquely owned)
            tv7=tv6;ti7=ti6; tv6=tv5;ti6=ti5; tv5=tv4;ti5=ti4; tv4=tv3;ti4=ti3;
            tv3=tv2;ti3=ti2; tv2=tv1;ti2=ti1; tv1=tv0;ti1=ti0; tv0=-3.4e38f;ti0=-1;
        }
        if (li == k) { sTopW[rtB*KSEL + k] = __expf(bv - m) * invd; sTopI[rtB*KSEL + k] = bi; }
    }
    __syncthreads();

    // ---- epilogue (LDS overlay over sC/sP/sL region) ----
    float* sH  = sm;           // [16][52]
    float* sUd = sm + 832;     // [16][12]
    float* sQ  = sm + 1024;    // [16][500]  q[j][e] per row

    const int g = tid >> 4, lg = tid & 15;
    const int row = row0 + g;
    const int rt_t = g*2, rt_s = g*2 + 1;
    const int uidx = is64 ? x32[4*row]   : x32[2*row];
    const int iidx = is64 ? x32[4*row+2] : x32[2*row+1];

    if (lg < DIMD) sUd[g*12 + lg] = suid[uidx*DIMD + lg];
    __syncthreads();

    // q[j][e] = sum_d uid_d * mw2[j,d,e]   (shared across the 8 experts)
    for (int t = lg; t < MDIM*DIMD; t += 16) {
        const int j = t / DIMD, e = t - j*DIMD;
        float q = 0.f;
        #pragma unroll
        for (int d = 0; d < DIMD; ++d) q += sUd[g*12 + d] * mw2[j*(DIMD*DIMD) + d*DIMD + e];
        sQ[g*500 + t] = q;
    }
    // tgt: ws50 = sum_k tw_k * C[i_k]
    for (int mm = lg; mm < MDIM; mm += 16) {
        float v = 0.f;
        #pragma unroll
        for (int k = 0; k < KSEL; ++k)
            v += sTopW[rt_t*KSEL + k] * Cm[sTopI[rt_t*KSEL + k]*MDIM + mm];
        sH[g*52 + mm] = v;
    }
    __syncthreads();

    float acc_e = 0.f, be = 0.f;
    if (lg < DIMD) {
        for (int m2 = 0; m2 < MDIM; ++m2) acc_e += sH[g*52 + m2] * w2[m2*DIMD + lg];
        #pragma unroll
        for (int d = 0; d < DIMD; ++d) be += sUd[g*12 + d] * mb2[d*DIMD + lg];
    }
    __syncthreads();

    for (int k = 0; k < KSEL; ++k) {
        const int   ik = sTopI[rt_s*KSEL + k];
        const float tw = sTopW[rt_s*KSEL + k];
        for (int j = lg; j < MDIM; j += 16) {
            float h = mb1[j];
            const float* crow = Cm + ik*MDIM;
            for (int t2 = 0; t2 < MDIM; ++t2) h += crow[t2] * mw1[t2*MDIM + j];
            #pragma unroll
            for (int d = 0; d < DIMD; ++d) h += sUd[g*12 + d] * mw1[(MDIM + d)*MDIM + j];
            sH[g*52 + j] = fmaxf(h, 0.f);
        }
        __syncthreads();
        if (lg < DIMD) {
            float se = be;
            for (int j = 0; j < MDIM; ++j) se += sH[g*52 + j] * sQ[g*500 + j*DIMD + lg];
            acc_e += tw * se;
        }
        __syncthreads();
    }

    float o = 0.f;
    if (lg < DIMD) o = acc_e * tiid[iidx*DIMD + lg];
    #pragma unroll
    for (int k = 8; k >= 1; k >>= 1) o += __shfl_xor(o, k, 16);
    if (lg == 0) out[row] = o;
}

extern "C" void kernel_launch(void* const* d_in, const int* in_sizes, int n_in,
                              void* d_out, int out_size, void* d_ws, size_t ws_size,
                              hipStream_t stream) {
    const int*   x32  = (const int*)d_in[0];
    const float* gsrc = (const float*)d_in[1];
    const float* gtgt = (const float*)d_in[2];
    const float* suid = (const float*)d_in[3];
    const float* tuid = (const float*)d_in[4];
    const float* tiid = (const float*)d_in[5];
    const float* Cm   = (const float*)d_in[6];
    const float* w1   = (const float*)d_in[7];
    const float* w2   = (const float*)d_in[8];
    const float* mw1  = (const float*)d_in[9];
    const float* mb1  = (const float*)d_in[10];
    const float* mw2  = (const float*)d_in[11];
    const float* mb2  = (const float*)d_in[12];
    hipLaunchKernelGGL(mf_fused, dim3(BROWS/RPB), dim3(256), 0, stream,
                       x32, gsrc, gtgt, suid, tuid, tiid, Cm, w1, w2, mw1, mb1, mw2, mb2,
                       (float*)d_out);
}

// Round 2
// 300.357 us; speedup vs baseline: 1.9027x; 1.9027x over previous
//
#include <hip/hip_runtime.h>
#include <hip/hip_bf16.h>

// MFBasedModel fused kernel, round 2: fp16-MFMA routing GEMM + branch-free
// smashed top-k selection + exact f32 top-12 recompute + fused MLP epilogue.
// One block = 16 rows (32 row-tasks = row x {tgt,src}); C staged per 128-cand
// chunk as swizzled fp16 in LDS.

#define BROWS 16384
#define CNUM  2048
#define KSEL  8
#define DIMD  10
#define MDIM  50
#define RPB   16
#define RTPB  32
#define CH    128
#define NCH   (CNUM/CH)
#define TAUI  0.1f
#define T12   12

// word offsets into smem (f32 words)
#define OFF_C    0        // 4096 w : sC16 [128][64] f16, XOR-swizzled
#define OFF_P16  4096     // 1024 w : sP16 [32][64] f16, XOR-swizzled
#define OFF_PF   5120     // 1664 w : sPf [32][52] f32
#define OFF_L    6784     // 4224 w : sL  [32][132] f32
#define OFF_TS   11008    // 32
#define OFF_T12  11040    // 384 (uint, smashed)
#define OFF_T12L 11424    // 384 (exact l)
#define OFF_TW   11808    // 256
#define OFF_TI   12064    // 256 (int)
#define OFF_UD   12320    // 192 : sUd [16][12]
#define SMEM_W   12512
// epilogue overlays (after routing done): sH at word 0 (832), sQ at 832 (8000)

typedef float    f32x4 __attribute__((ext_vector_type(4)));
typedef _Float16 half8 __attribute__((ext_vector_type(8)));
typedef float    flt2  __attribute__((ext_vector_type(2)));
typedef unsigned int uint_t;

__device__ __forceinline__ uint_t pkrtz(float a, float b) {
    auto h = __builtin_amdgcn_cvt_pkrtz(a, b);
    union { decltype(h) v; uint_t u; } c; c.v = h; return c.u;
}
__device__ __forceinline__ float gnoise(float u) {
    return -__logf(-__logf(u + 1e-20f) + 1e-20f);
}

__global__ __launch_bounds__(256, 3)
void mf_fused(const int* __restrict__ x32,
              const float* __restrict__ gsrc,
              const float* __restrict__ gtgt,
              const float* __restrict__ suid,
              const float* __restrict__ tuid,
              const float* __restrict__ tiid,
              const float* __restrict__ Cm,
              const float* __restrict__ w1,
              const float* __restrict__ w2,
              const float* __restrict__ mw1,
              const float* __restrict__ mb1,
              const float* __restrict__ mw2,
              const float* __restrict__ mb2,
              float* __restrict__ out)
{
    __shared__ __align__(16) float smem[SMEM_W];
    __shared__ int sFlag;
    uint_t* W   = (uint_t*)smem;
    float*  sPf = smem + OFF_PF;
    float*  sL  = smem + OFF_L;
    uint_t* T12u = (uint_t*)(smem + OFF_T12);

    const int tid  = threadIdx.x;
    const int row0 = blockIdx.x * RPB;

    // ---- x dtype detect (int64 high words all zero vs int32) ----
    if (tid == 0) sFlag = 1;
    __syncthreads();
    if (tid < 128) { if (x32[2*tid+1] != 0) atomicAnd(&sFlag, 0); }
    __syncthreads();
    const int is64 = sFlag;

    // ---- p = emb @ w1 (f32) -> sPf[32][52], cols 0..49 ----
    for (int t = tid; t < RTPB*MDIM; t += 256) {
        const int rt = t / MDIM, mm = t - rt*MDIM;
        const int r = row0 + (rt >> 1);
        const int uidx = is64 ? x32[4*r] : x32[2*r];
        const float* tab = (rt & 1) ? suid : tuid;
        float v = 0.f;
        #pragma unroll
        for (int d = 0; d < DIMD; ++d) v += tab[uidx*DIMD + d] * w1[d*MDIM + mm];
        sPf[rt*52 + mm] = v;
    }
    __syncthreads();

    // ---- sP16 [32][64] fp16, swizzled, zero-padded K 50..63 ----
    if (tid < 64) {
        const int rt = tid >> 1, hh = tid & 1;
        #pragma unroll
        for (int jj = 0; jj < 8; ++jj) {
            const int col0 = hh*32 + jj*4;
            float e0=0.f, e1=0.f, e2=0.f, e3=0.f;
            if (col0 < MDIM) {
                e0 = sPf[rt*52 + col0]; e1 = sPf[rt*52 + col0 + 1];
                if (col0 + 2 < MDIM) { e2 = sPf[rt*52 + col0 + 2]; e3 = sPf[rt*52 + col0 + 3]; }
            }
            const int wi = (OFF_P16 + rt*32 + hh*16 + jj*2) ^ ((rt & 7) << 2);
            *(uint2*)&W[wi] = make_uint2(pkrtz(e0, e1), pkrtz(e2, e3));
        }
    }

    // ---- stage C chunk as fp16 swizzled [128][64] ----
    const int srr = tid >> 1, shh = tid & 1;
    auto stageC = [&](int c0) {
        const float* crow = Cm + (c0 + srr) * MDIM;
        #pragma unroll
        for (int jj = 0; jj < 8; ++jj) {
            const int col0 = shh*32 + jj*4;
            float e0=0.f, e1=0.f, e2=0.f, e3=0.f;
            if (col0 < MDIM) {
                flt2 a = *(const flt2*)(crow + col0); e0 = a.x; e1 = a.y;
                if (col0 + 2 < MDIM) { flt2 b = *(const flt2*)(crow + col0 + 2); e2 = b.x; e3 = b.y; }
            }
            const int wi = (OFF_C + srr*32 + shh*16 + jj*2) ^ ((srr & 7) << 2);
            *(uint2*)&W[wi] = make_uint2(pkrtz(e0, e1), pkrtz(e2, e3));
        }
    };

    // MFMA lane decomposition
    const int lane = tid & 63, wv = tid >> 6;
    const int lr = lane & 15, lk = lane >> 4;
    const int mt = wv & 1, nh = wv >> 1;     // M-tile, N-half
    const int rtA = mt*16 + lr;
    const int aw0 = (OFF_P16 + rtA*32 + 0  + lk*4) ^ ((rtA & 7) << 2);
    const int aw1 = (OFF_P16 + rtA*32 + 16 + lk*4) ^ ((rtA & 7) << 2);

    // phase-B decomposition
    const int rtB = tid >> 3, li = tid & 7;

    float ts0 = 0.f, ts1 = 0.f;
    float q0=-3.4e38f,q1=-3.4e38f,q2=-3.4e38f,q3=-3.4e38f,
          q4=-3.4e38f,q5=-3.4e38f,q6=-3.4e38f,q7=-3.4e38f;

    stageC(0);
    __syncthreads();
    const half8 a0 = *(const half8*)&W[aw0];
    const half8 a1 = *(const half8*)&W[aw1];

    for (int ch = 0; ch < NCH; ++ch) {
        const int c0 = ch * CH;

        // ---- MFMA + gumbel noise -> sL[rt][lc] ----
        #pragma unroll
        for (int nt = 0; nt < 4; ++nt) {
            const int lc  = nh*64 + nt*16 + lr;
            const int bs0 = (OFF_C + lc*32 + 0  + lk*4) ^ ((lc & 7) << 2);
            const int bs1 = (OFF_C + lc*32 + 16 + lk*4) ^ ((lc & 7) << 2);
            const half8 b0 = *(const half8*)&W[bs0];
            const half8 b1 = *(const half8*)&W[bs1];
            f32x4 acc = {0.f, 0.f, 0.f, 0.f};
            acc = __builtin_amdgcn_mfma_f32_16x16x32_f16(a0, b0, acc, 0, 0, 0);
            acc = __builtin_amdgcn_mfma_f32_16x16x32_f16(a1, b1, acc, 0, 0, 0);
            #pragma unroll
            for (int r4 = 0; r4 < 4; ++r4) {
                const int rtl = mt*16 + lk*4 + r4;
                const int r = row0 + (rtl >> 1);
                const float u = ((r4 & 1) ? gsrc : gtgt)[(size_t)r*CNUM + c0 + lc];
                sL[rtl*132 + lc] = (acc[r4] + gnoise(u)) * TAUI;
            }
        }
        __syncthreads();

        // ---- stage next chunk (parallel with phase B) ----
        if (ch + 1 < NCH) stageC((ch + 1) * CH);

        // ---- phase B: exp-sum + smashed branch-free top-8 insert ----
        {
            f32x4 vv[4];
            #pragma unroll
            for (int j4 = 0; j4 < 4; ++j4)
                vv[j4] = *(const f32x4*)(sL + rtB*132 + li*16 + j4*4);
            #pragma unroll
            for (int j4 = 0; j4 < 4; ++j4) {
                #pragma unroll
                for (int e = 0; e < 4; ++e) {
                    const float l = vv[j4][e];
                    if (e & 1) ts1 += __expf(l); else ts0 += __expf(l);
                    const uint_t gc = (uint_t)(c0 + li*16 + j4*4 + e);
                    const float xs = __uint_as_float((__float_as_uint(l) & 0xFFFFF800u) | gc);
                    // sorted ascending insert, drop min: 15 min/max ops
                    q0 = fmaxf(q0, fminf(q1, xs));
                    q1 = fmaxf(q1, fminf(q2, xs));
                    q2 = fmaxf(q2, fminf(q3, xs));
                    q3 = fmaxf(q3, fminf(q4, xs));
                    q4 = fmaxf(q4, fminf(q5, xs));
                    q5 = fmaxf(q5, fminf(q6, xs));
                    q6 = fmaxf(q6, fminf(q7, xs));
                    q7 = fmaxf(q7, xs);
                }
            }
        }
        __syncthreads();
    }

    // ---- group exp-sum + merged top-12 tournament (8 lanes per rt) ----
    {
        float ts = ts0 + ts1;
        ts += __shfl_xor(ts, 1, 8); ts += __shfl_xor(ts, 2, 8); ts += __shfl_xor(ts, 4, 8);
        if (li == 0) smem[OFF_TS + rtB] = ts;
        #pragma unroll
        for (int k = 0; k < T12; ++k) {
            float gm = q7;
            gm = fmaxf(gm, __shfl_xor(gm, 1, 8));
            gm = fmaxf(gm, __shfl_xor(gm, 2, 8));
            gm = fmaxf(gm, __shfl_xor(gm, 4, 8));
            if (q7 == gm) { q7=q6; q6=q5; q5=q4; q4=q3; q3=q2; q2=q1; q1=q0; q0=-3.4e38f; }
            if (li == (k & 7)) T12u[rtB*T12 + k] = __float_as_uint(gm);
        }
    }
    __syncthreads();

    // ---- exact f32 recompute of top-12 l values ----
    for (int T = tid; T < RTPB*T12; T += 256) {
        const int rt = T / T12, j = T - rt*T12;
        const int idx = (int)(T12u[rt*T12 + j] & 2047u);
        const float* pf = sPf + rt*52;
        const float* cr = Cm + idx*MDIM;
        float s = 0.f;
        #pragma unroll
        for (int k2 = 0; k2 < 25; ++k2) {
            flt2 c = *(const flt2*)(cr + k2*2);
            s += pf[2*k2] * c.x + pf[2*k2+1] * c.y;
        }
        const int r = row0 + (rt >> 1);
        const float u = ((rt & 1) ? gsrc : gtgt)[(size_t)r*CNUM + idx];
        smem[OFF_T12L + rt*T12 + j] = (s + gnoise(u)) * TAUI;
    }
    __syncthreads();

    // ---- finalize: exact top-8 of the 12 (tiebreak lower index), weights ----
    if (tid < RTPB) {
        const int rt = tid;
        const float inv = 1.0f / smem[OFF_TS + rt];
        float lv[T12]; int iv[T12];
        #pragma unroll
        for (int j = 0; j < T12; ++j) {
            lv[j] = smem[OFF_T12L + rt*T12 + j];
            iv[j] = (int)(T12u[rt*T12 + j] & 2047u);
        }
        uint_t used = 0;
        #pragma unroll
        for (int k = 0; k < KSEL; ++k) {
            float bl = -3.4e38f; int bi = 1 << 30; int bj = 0;
            #pragma unroll
            for (int j = 0; j < T12; ++j) {
                const bool ok = !((used >> j) & 1);
                if (ok && (lv[j] > bl || (lv[j] == bl && iv[j] < bi))) { bl = lv[j]; bi = iv[j]; bj = j; }
            }
            used |= 1u << bj;
            smem[OFF_TW + rt*KSEL + k] = __expf(bl) * inv;
            ((int*)smem)[OFF_TI + rt*KSEL + k] = bi;
        }
    }
    __syncthreads();

    // ---- epilogue: MLP mixture (overlays sC/sP16/sPf regions) ----
    float* sH    = smem;                 // [16][52]
    float* sQ    = smem + 832;           // [16][500]
    float* sUd   = smem + OFF_UD;        // [16][12]
    float* sTopW = smem + OFF_TW;
    int*   sTopI = (int*)smem + OFF_TI;

    const int g = tid >> 4, lg = tid & 15;
    const int row = row0 + g;
    const int rt_t = g*2, rt_s = g*2 + 1;
    const int uidx = is64 ? x32[4*row]     : x32[2*row];
    const int iidx = is64 ? x32[4*row + 2] : x32[2*row + 1];

    if (lg < DIMD) sUd[g*12 + lg] = suid[uidx*DIMD + lg];
    __syncthreads();

    // q[j][e] = sum_d uid_d * mw2[j,d,e] (shared across the 8 experts)
    for (int t = lg; t < MDIM*DIMD; t += 16) {
        const int j = t / DIMD, e = t - j*DIMD;
        float q = 0.f;
        #pragma unroll
        for (int d = 0; d < DIMD; ++d) q += sUd[g*12 + d] * mw2[j*(DIMD*DIMD) + d*DIMD + e];
        sQ[g*500 + t] = q;
    }
    // tgt: ws50 = sum_k tw_k * C[i_k]
    for (int mm = lg; mm < MDIM; mm += 16) {
        float v = 0.f;
        #pragma unroll
        for (int k = 0; k < KSEL; ++k)
            v += sTopW[rt_t*KSEL + k] * Cm[sTopI[rt_t*KSEL + k]*MDIM + mm];
        sH[g*52 + mm] = v;
    }
    __syncthreads();

    float acc_e = 0.f, be = 0.f;
    if (lg < DIMD) {
        for (int m2 = 0; m2 < MDIM; ++m2) acc_e += sH[g*52 + m2] * w2[m2*DIMD + lg];
        #pragma unroll
        for (int d = 0; d < DIMD; ++d) be += sUd[g*12 + d] * mb2[d*DIMD + lg];
    }
    __syncthreads();

    for (int k = 0; k < KSEL; ++k) {
        const int   ik = sTopI[rt_s*KSEL + k];
        const float tw = sTopW[rt_s*KSEL + k];
        for (int j = lg; j < MDIM; j += 16) {
            float h = mb1[j];
            const float* crow = Cm + ik*MDIM;
            for (int t2 = 0; t2 < MDIM; ++t2) h += crow[t2] * mw1[t2*MDIM + j];
            #pragma unroll
            for (int d = 0; d < DIMD; ++d) h += sUd[g*12 + d] * mw1[(MDIM + d)*MDIM + j];
            sH[g*52 + j] = fmaxf(h, 0.f);
        }
        __syncthreads();
        if (lg < DIMD) {
            float se = be;
            for (int j = 0; j < MDIM; ++j) se += sH[g*52 + j] * sQ[g*500 + j*DIMD + lg];
            acc_e += tw * se;
        }
        __syncthreads();
    }

    float o = 0.f;
    if (lg < DIMD) o = acc_e * tiid[iidx*DIMD + lg];
    #pragma unroll
    for (int k = 8; k >= 1; k >>= 1) o += __shfl_xor(o, k, 16);
    if (lg == 0) out[row] = o;
}

extern "C" void kernel_launch(void* const* d_in, const int* in_sizes, int n_in,
                              void* d_out, int out_size, void* d_ws, size_t ws_size,
                              hipStream_t stream) {
    (void)in_sizes; (void)n_in; (void)out_size; (void)d_ws; (void)ws_size;
    const int*   x32  = (const int*)d_in[0];
    const float* gsrc = (const float*)d_in[1];
    const float* gtgt = (const float*)d_in[2];
    const float* suid = (const float*)d_in[3];
    const float* tuid = (const float*)d_in[4];
    const float* tiid = (const float*)d_in[5];
    const float* Cm   = (const float*)d_in[6];
    const float* w1   = (const float*)d_in[7];
    const float* w2   = (const float*)d_in[8];
    const float* mw1  = (const float*)d_in[9];
    const float* mb1  = (const float*)d_in[10];
    const float* mw2  = (const float*)d_in[11];
    const float* mb2  = (const float*)d_in[12];
    hipLaunchKernelGGL(mf_fused, dim3(BROWS/RPB), dim3(256), 0, stream,
                       x32, gsrc, gtgt, suid, tuid, tiid, Cm, w1, w2, mw1, mb1, mw2, mb2,
                       (float*)d_out);
}

// Round 3
// 290.605 us; speedup vs baseline: 1.9665x; 1.0336x over previous
//
#include <hip/hip_runtime.h>
#include <hip/hip_bf16.h>

// MFBasedModel fused kernel, round 3: swapped-operand MFMA (S^T) so routing
// selection is register-resident per lane; one barrier per chunk; C pre-
// converted to fp16 in d_ws by a pre-kernel; gumbel loaded as per-lane float4.

#define BROWS 16384
#define CNUM  2048
#define KSEL  8
#define DIMD  10
#define MDIM  50
#define RPB   16
#define RTPB  32
#define CH    128
#define NCH   (CNUM/CH)
#define TAUI  0.1f
#define T24   24

// LDS word offsets
#define OFF_C0   0        // 4096 w : chunk buf 0, fp16 [128][64] swizzled
#define OFF_C1   4096     // 4096 w : chunk buf 1
#define OFF_PF   8192     // 1664 w : sPf [32][52] f32 (cols 50,51 zero)
#define OFF_T24  9856     // 768 w  : smashed top-12 x 2 halves per rt (uint)
#define OFF_T24L 10624    // 768 w  : exact l per entry
#define OFF_TS   11392    // 64 w   : exp-sum partials [rt][half]
#define OFF_TW   11456    // 256 w
#define OFF_TI   11712    // 256 w (int)
#define OFF_UD   11968    // 192 w : sUd [16][12]
#define SMEM_W   12160

typedef float    f32x4 __attribute__((ext_vector_type(4)));
typedef _Float16 half8 __attribute__((ext_vector_type(8)));
typedef float    flt2  __attribute__((ext_vector_type(2)));
typedef unsigned int u32;

__device__ __forceinline__ u32 pkrtz(float a, float b) {
    auto h = __builtin_amdgcn_cvt_pkrtz(a, b);
    union { decltype(h) v; u32 u; } c; c.v = h; return c.u;
}
__device__ __forceinline__ float gnoise(float u) {
    return -__logf(-__logf(u + 1e-20f) + 1e-20f);
}

// ---- pre-kernel: C f32 [2048][50] -> fp16 [2048][32 words] zero-padded ----
__global__ void cvtC(const float* __restrict__ Cm, u32* __restrict__ C16) {
    const int j = blockIdx.x * 256 + threadIdx.x;   // 65536 words
    const int cand = j >> 5, w = j & 31, k = 2 * w;
    const float a = (k < MDIM)     ? Cm[cand*MDIM + k]     : 0.f;
    const float b = (k + 1 < MDIM) ? Cm[cand*MDIM + k + 1] : 0.f;
    C16[j] = pkrtz(a, b);
}

template<bool PRE>
__global__ __launch_bounds__(256, 3)
void mf_fused(const int* __restrict__ x32,
              const float* __restrict__ gsrc,
              const float* __restrict__ gtgt,
              const float* __restrict__ suid,
              const float* __restrict__ tuid,
              const float* __restrict__ tiid,
              const float* __restrict__ Cm,
              const float* __restrict__ w1,
              const float* __restrict__ w2,
              const float* __restrict__ mw1,
              const float* __restrict__ mb1,
              const float* __restrict__ mw2,
              const float* __restrict__ mb2,
              const u32* __restrict__ C16,
              float* __restrict__ out)
{
    __shared__ __align__(16) float smem[SMEM_W];
    __shared__ int sFlag;
    u32*   W    = (u32*)smem;
    float* sPf  = smem + OFF_PF;
    u32*   T24u = (u32*)(smem + OFF_T24);
    float* T24l = smem + OFF_T24L;

    const int tid  = threadIdx.x;
    const int row0 = blockIdx.x * RPB;

    // ---- x dtype detect ----
    if (tid == 0) sFlag = 1;
    __syncthreads();
    if (tid < 128) { if (x32[2*tid+1] != 0) atomicAnd(&sFlag, 0); }
    __syncthreads();
    const int is64 = sFlag;

    // ---- sPf = emb @ w1 (f32), zero-padded to 52 cols ----
    for (int t = tid; t < RTPB*52; t += 256) {
        const int rt = t / 52, mm = t - rt*52;
        float v = 0.f;
        if (mm < MDIM) {
            const int r = row0 + (rt >> 1);
            const int uidx = is64 ? x32[4*r] : x32[2*r];
            const float* tab = (rt & 1) ? suid : tuid;
            #pragma unroll
            for (int d = 0; d < DIMD; ++d) v += tab[uidx*DIMD + d] * w1[d*MDIM + mm];
        }
        sPf[t] = v;
    }

    // ---- staging (reg <- global, swizzled ds_write) ----
    u32 sw[16];
    const int xorv = ((tid >> 3) & 7) << 2;
    auto issue = [&](int ch) {
        if (PRE) {
            const uint4* src = (const uint4*)C16;
            #pragma unroll
            for (int i = 0; i < 4; ++i) {
                uint4 t4 = src[ch*1024 + i*256 + tid];
                sw[i*4+0] = t4.x; sw[i*4+1] = t4.y; sw[i*4+2] = t4.z; sw[i*4+3] = t4.w;
            }
        } else {
            #pragma unroll
            for (int i = 0; i < 4; ++i)
                #pragma unroll
                for (int w2i = 0; w2i < 4; ++w2i) {
                    const int cand = ch*CH + (tid >> 3) + i*32;
                    const int widx = (tid*4 + w2i) & 31, k = 2*widx;
                    const float a = (k < MDIM)     ? Cm[cand*MDIM + k]     : 0.f;
                    const float b = (k + 1 < MDIM) ? Cm[cand*MDIM + k + 1] : 0.f;
                    sw[i*4 + w2i] = pkrtz(a, b);
                }
        }
    };
    auto commit = [&](int buf) {
        u32* B = W + buf*4096;
        #pragma unroll
        for (int i = 0; i < 4; ++i)
            *(uint4*)&B[(tid*4 + i*1024) ^ xorv] =
                make_uint4(sw[i*4], sw[i*4+1], sw[i*4+2], sw[i*4+3]);
    };

    issue(0); commit(0);
    __syncthreads();

    // ---- lane decomposition: wave w -> rt-group g=w&1, cand-half h=w>>1 ----
    const int lane = tid & 63, wv = tid >> 6;
    const int lr = lane & 15, lk = lane >> 4;
    const int g = wv & 1, h = wv >> 1;
    const int rt = g*16 + lr;
    const int xorr = (lr & 7) << 2;
    const float* up = ((lr & 1) ? gsrc : gtgt) + (size_t)(row0 + g*8 + (lr >> 1)) * CNUM;

    // B-fragments: P16[rt][k] built in regs from sPf
    half8 b0, b1;
    {
        union { u32 u[4]; half8 v; } c0, c1;
        #pragma unroll
        for (int jj = 0; jj < 4; ++jj) {
            const int k0 = lk*8 + jj*2;
            c0.u[jj] = pkrtz(sPf[rt*52 + k0], sPf[rt*52 + k0 + 1]);
            const int k1 = 32 + lk*8 + jj*2;
            const float e0 = (k1     < 52) ? sPf[rt*52 + k1]     : 0.f;
            const float e1 = (k1 + 1 < 52) ? sPf[rt*52 + k1 + 1] : 0.f;
            c1.u[jj] = pkrtz(e0, e1);
        }
        b0 = c0.v; b1 = c1.v;
    }

    float ts = 0.f;
    float q0=-3.4e38f,q1=-3.4e38f,q2=-3.4e38f,q3=-3.4e38f,
          q4=-3.4e38f,q5=-3.4e38f,q6=-3.4e38f,q7=-3.4e38f;

    for (int ch = 0; ch < NCH; ++ch) {
        if (ch + 1 < NCH) issue(ch + 1);
        const u32* Bf = W + (ch & 1)*4096;
        #pragma unroll
        for (int nt = 0; nt < 4; ++nt) {
            const int cl = h*64 + nt*16;                  // tile cand base (local)
            const int wb = (cl + lr) * 32;
            const half8 a0 = *(const half8*)&Bf[(wb +      lk*4) ^ xorr];
            const half8 a1 = *(const half8*)&Bf[(wb + 16 + lk*4) ^ xorr];
            f32x4 acc = {0.f, 0.f, 0.f, 0.f};
            acc = __builtin_amdgcn_mfma_f32_16x16x32_f16(a0, b0, acc, 0, 0, 0);
            acc = __builtin_amdgcn_mfma_f32_16x16x32_f16(a1, b1, acc, 0, 0, 0);
            const f32x4 u4 = *(const f32x4*)(up + ch*CH + cl + lk*4);
            const int cg = ch*CH + cl + lk*4;
            #pragma unroll
            for (int r4 = 0; r4 < 4; ++r4) {
                const float l = (acc[r4] + gnoise(u4[r4])) * TAUI;
                ts += __expf(l);
                const float xs = __uint_as_float(
                    (__float_as_uint(l) & 0xFFFFF800u) | (u32)(cg + r4));
                q0 = fmaxf(q0, fminf(q1, xs));
                q1 = fmaxf(q1, fminf(q2, xs));
                q2 = fmaxf(q2, fminf(q3, xs));
                q3 = fmaxf(q3, fminf(q4, xs));
                q4 = fmaxf(q4, fminf(q5, xs));
                q5 = fmaxf(q5, fminf(q6, xs));
                q6 = fmaxf(q6, fminf(q7, xs));
                q7 = fmaxf(q7, xs);
            }
        }
        if (ch + 1 < NCH) commit((ch + 1) & 1);
        __syncthreads();
    }

    // ---- merge over lk lanes (xor 16/32): exp-sum + top-12 tournament ----
    {
        float tss = ts;
        tss += __shfl_xor(tss, 16); tss += __shfl_xor(tss, 32);
        if (lk == 0) smem[OFF_TS + rt*2 + h] = tss;
        #pragma unroll
        for (int k = 0; k < 12; ++k) {
            float gm = fmaxf(q7, __shfl_xor(q7, 16));
            gm = fmaxf(gm, __shfl_xor(gm, 32));
            if (q7 == gm) {
                T24u[rt*T24 + h*12 + k] = __float_as_uint(q7);
                q7=q6; q6=q5; q5=q4; q4=q3; q3=q2; q2=q1; q1=q0; q0=-3.4e38f;
            }
        }
    }
    __syncthreads();

    // ---- exact f32 recompute of the 24 candidates per rt ----
    for (int e = tid; e < RTPB*T24; e += 256) {
        const int ert = e / T24;
        const int idx = (int)(T24u[e] & 2047u);
        const float* pf = sPf + ert*52;
        const float* cr = Cm + idx*MDIM;
        float s = 0.f;
        #pragma unroll
        for (int k2 = 0; k2 < 25; ++k2) {
            flt2 c = *(const flt2*)(cr + k2*2);
            s += pf[2*k2] * c.x + pf[2*k2+1] * c.y;
        }
        const int r = row0 + (ert >> 1);
        const float u = ((ert & 1) ? gsrc : gtgt)[(size_t)r*CNUM + idx];
        T24l[e] = (s + gnoise(u)) * TAUI;
    }
    __syncthreads();

    // ---- exact top-8 of 24 (tiebreak lower index), weights ----
    if (tid < RTPB) {
        const int rrt = tid;
        const float inv = 1.0f / (smem[OFF_TS + rrt*2] + smem[OFF_TS + rrt*2 + 1]);
        float lv[T24]; int iv[T24];
        #pragma unroll
        for (int j = 0; j < T24; ++j) {
            lv[j] = T24l[rrt*T24 + j];
            iv[j] = (int)(T24u[rrt*T24 + j] & 2047u);
        }
        u32 used = 0;
        #pragma unroll
        for (int k = 0; k < KSEL; ++k) {
            float bl = -3.4e38f; int bi = 1 << 30; int bj = 0;
            #pragma unroll
            for (int j = 0; j < T24; ++j) {
                const bool ok = !((used >> j) & 1);
                if (ok && (lv[j] > bl || (lv[j] == bl && iv[j] < bi))) { bl = lv[j]; bi = iv[j]; bj = j; }
            }
            used |= 1u << bj;
            smem[OFF_TW + rrt*KSEL + k] = __expf(bl) * inv;
            ((int*)smem)[OFF_TI + rrt*KSEL + k] = bi;
        }
    }
    __syncthreads();

    // ---- epilogue: MLP mixture (overlays chunk-buffer region) ----
    float* sH    = smem;                 // [16][52]
    float* sQ    = smem + 832;           // [16][500]
    float* sUd   = smem + OFF_UD;
    float* sTopW = smem + OFF_TW;
    int*   sTopI = (int*)smem + OFF_TI;

    const int gg = tid >> 4, lg = tid & 15;
    const int row = row0 + gg;
    const int rt_t = gg*2, rt_s = gg*2 + 1;
    const int uidx = is64 ? x32[4*row]     : x32[2*row];
    const int iidx = is64 ? x32[4*row + 2] : x32[2*row + 1];

    if (lg < DIMD) sUd[gg*12 + lg] = suid[uidx*DIMD + lg];
    __syncthreads();

    for (int t = lg; t < MDIM*DIMD; t += 16) {
        const int j = t / DIMD, e = t - j*DIMD;
        float q = 0.f;
        #pragma unroll
        for (int d = 0; d < DIMD; ++d) q += sUd[gg*12 + d] * mw2[j*(DIMD*DIMD) + d*DIMD + e];
        sQ[gg*500 + t] = q;
    }
    for (int mm = lg; mm < MDIM; mm += 16) {
        float v = 0.f;
        #pragma unroll
        for (int k = 0; k < KSEL; ++k)
            v += sTopW[rt_t*KSEL + k] * Cm[sTopI[rt_t*KSEL + k]*MDIM + mm];
        sH[gg*52 + mm] = v;
    }
    __syncthreads();

    float acc_e = 0.f, be = 0.f;
    if (lg < DIMD) {
        for (int m2 = 0; m2 < MDIM; ++m2) acc_e += sH[gg*52 + m2] * w2[m2*DIMD + lg];
        #pragma unroll
        for (int d = 0; d < DIMD; ++d) be += sUd[gg*12 + d] * mb2[d*DIMD + lg];
    }
    __syncthreads();

    for (int k = 0; k < KSEL; ++k) {
        const int   ik = sTopI[rt_s*KSEL + k];
        const float tw = sTopW[rt_s*KSEL + k];
        for (int j = lg; j < MDIM; j += 16) {
            float hh = mb1[j];
            const float* crow = Cm + ik*MDIM;
            for (int t2 = 0; t2 < MDIM; ++t2) hh += crow[t2] * mw1[t2*MDIM + j];
            #pragma unroll
            for (int d = 0; d < DIMD; ++d) hh += sUd[gg*12 + d] * mw1[(MDIM + d)*MDIM + j];
            sH[gg*52 + j] = fmaxf(hh, 0.f);
        }
        __syncthreads();
        if (lg < DIMD) {
            float se = be;
            for (int j = 0; j < MDIM; ++j) se += sH[gg*52 + j] * sQ[gg*500 + j*DIMD + lg];
            acc_e += tw * se;
        }
        __syncthreads();
    }

    float o = 0.f;
    if (lg < DIMD) o = acc_e * tiid[iidx*DIMD + lg];
    #pragma unroll
    for (int k = 8; k >= 1; k >>= 1) o += __shfl_xor(o, k, 16);
    if (lg == 0) out[row] = o;
}

extern "C" void kernel_launch(void* const* d_in, const int* in_sizes, int n_in,
                              void* d_out, int out_size, void* d_ws, size_t ws_size,
                              hipStream_t stream) {
    (void)in_sizes; (void)n_in; (void)out_size;
    const int*   x32  = (const int*)d_in[0];
    const float* gsrc = (const float*)d_in[1];
    const float* gtgt = (const float*)d_in[2];
    const float* suid = (const float*)d_in[3];
    const float* tuid = (const float*)d_in[4];
    const float* tiid = (const float*)d_in[5];
    const float* Cm   = (const float*)d_in[6];
    const float* w1   = (const float*)d_in[7];
    const float* w2   = (const float*)d_in[8];
    const float* mw1  = (const float*)d_in[9];
    const float* mb1  = (const float*)d_in[10];
    const float* mw2  = (const float*)d_in[11];
    const float* mb2  = (const float*)d_in[12];
    u32* C16 = (u32*)d_ws;

    if (ws_size >= 262144) {
        hipLaunchKernelGGL(cvtC, dim3(256), dim3(256), 0, stream, Cm, C16);
        hipLaunchKernelGGL(mf_fused<true>, dim3(BROWS/RPB), dim3(256), 0, stream,
                           x32, gsrc, gtgt, suid, tuid, tiid, Cm, w1, w2, mw1, mb1, mw2, mb2,
                           C16, (float*)d_out);
    } else {
        hipLaunchKernelGGL(mf_fused<false>, dim3(BROWS/RPB), dim3(256), 0, stream,
                           x32, gsrc, gtgt, suid, tuid, tiid, Cm, w1, w2, mw1, mb1, mw2, mb2,
                           C16, (float*)d_out);
    }
}

// Round 4
// 282.507 us; speedup vs baseline: 2.0229x; 1.0287x over previous
//
#include <hip/hip_runtime.h>
#include <hip/hip_bf16.h>

// MFBasedModel fused kernel, round 4: barrier-free main loop. C (fp16, 256 KB)
// is L2-resident and MFMA A-fragments are loaded directly from global; the
// gumbel stream is per-lane float4. Selection stays register-resident
// (swapped-operand MFMA + smashed branch-free top-8, exact f32 recompute).

#define BROWS 16384
#define CNUM  2048
#define KSEL  8
#define DIMD  10
#define MDIM  50
#define RPB   16
#define RTPB  32
#define TAUI  0.1f
#define T24   24

// LDS word offsets
#define OFF_PF   0      // 1664 w : sPf [32][52] f32 (cols 50,51 zero)
#define OFF_T24  1664   // 768 w  : smashed top-12 x 2 halves per rt (uint)
#define OFF_T24L 2432   // 768 w  : exact l per entry
#define OFF_TS   3200   // 64 w   : exp-sum partials [rt][half]
#define OFF_TW   8832   // 256 w
#define OFF_TI   9088   // 256 w (int)
#define OFF_UD   9344   // 192 w : sUd [16][12]
#define SMEM_W   9536
// epilogue overlay: sH = smem+0 (832 w), sQ = smem+832 (8000 w)

typedef float    f32x4 __attribute__((ext_vector_type(4)));
typedef _Float16 half8 __attribute__((ext_vector_type(8)));
typedef float    flt2  __attribute__((ext_vector_type(2)));
typedef unsigned int u32;

__device__ __forceinline__ u32 pkrtz(float a, float b) {
    auto h = __builtin_amdgcn_cvt_pkrtz(a, b);
    union { decltype(h) v; u32 u; } c; c.v = h; return c.u;
}
__device__ __forceinline__ float gnoise(float u) {
    return -__logf(-__logf(u + 1e-20f) + 1e-20f);
}

// ---- pre-kernel: C f32 [2048][50] -> fp16 [2048][32 words] zero-padded ----
__global__ void cvtC(const float* __restrict__ Cm, u32* __restrict__ C16) {
    const int j = blockIdx.x * 256 + threadIdx.x;   // 65536 words
    const int cand = j >> 5, w = j & 31, k = 2 * w;
    const float a = (k < MDIM)     ? Cm[cand*MDIM + k]     : 0.f;
    const float b = (k + 1 < MDIM) ? Cm[cand*MDIM + k + 1] : 0.f;
    C16[j] = pkrtz(a, b);
}

template<bool PRE>
__global__ __launch_bounds__(256, 4)
void mf_fused(const int* __restrict__ x32,
              const float* __restrict__ gsrc,
              const float* __restrict__ gtgt,
              const float* __restrict__ suid,
              const float* __restrict__ tuid,
              const float* __restrict__ tiid,
              const float* __restrict__ Cm,
              const float* __restrict__ w1,
              const float* __restrict__ w2,
              const float* __restrict__ mw1,
              const float* __restrict__ mb1,
              const float* __restrict__ mw2,
              const float* __restrict__ mb2,
              const u32* __restrict__ C16,
              float* __restrict__ out)
{
    __shared__ __align__(16) float smem[SMEM_W];
    __shared__ int sFlag;
    float* sPf  = smem + OFF_PF;
    u32*   T24u = (u32*)(smem + OFF_T24);
    float* T24l = smem + OFF_T24L;

    const int tid  = threadIdx.x;
    const int row0 = blockIdx.x * RPB;

    // ---- x dtype detect ----
    if (tid == 0) sFlag = 1;
    __syncthreads();
    if (tid < 128) { if (x32[2*tid+1] != 0) atomicAnd(&sFlag, 0); }
    __syncthreads();
    const int is64 = sFlag;

    // ---- sPf = emb @ w1 (f32), zero-padded to 52 cols ----
    for (int t = tid; t < RTPB*52; t += 256) {
        const int rt = t / 52, mm = t - rt*52;
        float v = 0.f;
        if (mm < MDIM) {
            const int r = row0 + (rt >> 1);
            const int uidx = is64 ? x32[4*r] : x32[2*r];
            const float* tab = (rt & 1) ? suid : tuid;
            #pragma unroll
            for (int d = 0; d < DIMD; ++d) v += tab[uidx*DIMD + d] * w1[d*MDIM + mm];
        }
        sPf[t] = v;
    }
    __syncthreads();

    // ---- lane decomposition: wave wv -> rt-group g=wv&1, cand-half h=wv>>1 ----
    const int lane = tid & 63, wv = tid >> 6;
    const int lr = lane & 15, lk = lane >> 4;
    const int g = wv & 1, h = wv >> 1;
    const int rt = g*16 + lr;
    const float* up = ((lr & 1) ? gsrc : gtgt) + (size_t)(row0 + g*8 + (lr >> 1)) * CNUM;

    // B-fragments: P16[rt][k] built in regs from sPf
    half8 b0, b1;
    {
        union { u32 u[4]; half8 v; } c0, c1;
        #pragma unroll
        for (int jj = 0; jj < 4; ++jj) {
            const int k0 = lk*8 + jj*2;
            c0.u[jj] = pkrtz(sPf[rt*52 + k0], sPf[rt*52 + k0 + 1]);
            const int k1 = 32 + lk*8 + jj*2;
            const float e0 = (k1     < 52) ? sPf[rt*52 + k1]     : 0.f;
            const float e1 = (k1 + 1 < 52) ? sPf[rt*52 + k1 + 1] : 0.f;
            c1.u[jj] = pkrtz(e0, e1);
        }
        b0 = c0.v; b1 = c1.v;
    }

    float ts = 0.f;
    float q0=-3.4e38f,q1=-3.4e38f,q2=-3.4e38f,q3=-3.4e38f,
          q4=-3.4e38f,q5=-3.4e38f,q6=-3.4e38f,q7=-3.4e38f;

    // ---- barrier-free main loop: 64 candidate tiles of 16 per wave ----
    #pragma unroll 4
    for (int ti = 0; ti < 64; ++ti) {
        const int cb = ((ti >> 2) << 7) + h*64 + ((ti & 3) << 4);
        half8 a0, a1;
        if (PRE) {
            const u32* cr = C16 + (size_t)(cb + lr)*32 + lk*4;
            a0 = *(const half8*)cr;
            a1 = *(const half8*)(cr + 16);
        } else {
            const float* cr = Cm + (size_t)(cb + lr)*MDIM;
            union { u32 u[4]; half8 v; } c0, c1;
            #pragma unroll
            for (int jj = 0; jj < 4; ++jj) {
                const int k0 = lk*8 + jj*2;
                c0.u[jj] = pkrtz(cr[k0], cr[k0+1]);
                const int k1 = 32 + lk*8 + jj*2;
                const float e0 = (k1     < MDIM) ? cr[k1]     : 0.f;
                const float e1 = (k1 + 1 < MDIM) ? cr[k1+1] : 0.f;
                c1.u[jj] = pkrtz(e0, e1);
            }
            a0 = c0.v; a1 = c1.v;
        }
        f32x4 acc = {0.f, 0.f, 0.f, 0.f};
        acc = __builtin_amdgcn_mfma_f32_16x16x32_f16(a0, b0, acc, 0, 0, 0);
        acc = __builtin_amdgcn_mfma_f32_16x16x32_f16(a1, b1, acc, 0, 0, 0);
        const f32x4 u4 = *(const f32x4*)(up + cb + lk*4);
        const int cg = cb + lk*4;
        #pragma unroll
        for (int r4 = 0; r4 < 4; ++r4) {
            const float l = (acc[r4] + gnoise(u4[r4])) * TAUI;
            ts += __expf(l);
            const float xs = __uint_as_float(
                (__float_as_uint(l) & 0xFFFFF800u) | (u32)(cg + r4));
            q0 = fmaxf(q0, fminf(q1, xs));
            q1 = fmaxf(q1, fminf(q2, xs));
            q2 = fmaxf(q2, fminf(q3, xs));
            q3 = fmaxf(q3, fminf(q4, xs));
            q4 = fmaxf(q4, fminf(q5, xs));
            q5 = fmaxf(q5, fminf(q6, xs));
            q6 = fmaxf(q6, fminf(q7, xs));
            q7 = fmaxf(q7, xs);
        }
    }

    // ---- merge over lk lanes (xor 16/32): exp-sum + top-12 tournament ----
    {
        float tss = ts;
        tss += __shfl_xor(tss, 16); tss += __shfl_xor(tss, 32);
        if (lk == 0) smem[OFF_TS + rt*2 + h] = tss;
        #pragma unroll
        for (int k = 0; k < 12; ++k) {
            float gm = fmaxf(q7, __shfl_xor(q7, 16));
            gm = fmaxf(gm, __shfl_xor(gm, 32));
            if (q7 == gm) {
                T24u[rt*T24 + h*12 + k] = __float_as_uint(q7);
                q7=q6; q6=q5; q5=q4; q4=q3; q3=q2; q2=q1; q1=q0; q0=-3.4e38f;
            }
        }
    }
    __syncthreads();

    // ---- exact f32 recompute of the 24 candidates per rt ----
    for (int e = tid; e < RTPB*T24; e += 256) {
        const int ert = e / T24;
        const int idx = (int)(T24u[e] & 2047u);
        const float* pf = sPf + ert*52;
        const float* cr = Cm + idx*MDIM;
        float s = 0.f;
        #pragma unroll
        for (int k2 = 0; k2 < 25; ++k2) {
            flt2 c = *(const flt2*)(cr + k2*2);
            s += pf[2*k2] * c.x + pf[2*k2+1] * c.y;
        }
        const int r = row0 + (ert >> 1);
        const float u = ((ert & 1) ? gsrc : gtgt)[(size_t)r*CNUM + idx];
        T24l[e] = (s + gnoise(u)) * TAUI;
    }
    __syncthreads();

    // ---- exact top-8 of 24 (tiebreak lower index), weights ----
    if (tid < RTPB) {
        const int rrt = tid;
        const float inv = 1.0f / (smem[OFF_TS + rrt*2] + smem[OFF_TS + rrt*2 + 1]);
        float lv[T24]; int iv[T24];
        #pragma unroll
        for (int j = 0; j < T24; ++j) {
            lv[j] = T24l[rrt*T24 + j];
            iv[j] = (int)(T24u[rrt*T24 + j] & 2047u);
        }
        u32 used = 0;
        #pragma unroll
        for (int k = 0; k < KSEL; ++k) {
            float bl = -3.4e38f; int bi = 1 << 30; int bj = 0;
            #pragma unroll
            for (int j = 0; j < T24; ++j) {
                const bool ok = !((used >> j) & 1);
                if (ok && (lv[j] > bl || (lv[j] == bl && iv[j] < bi))) { bl = lv[j]; bi = iv[j]; bj = j; }
            }
            used |= 1u << bj;
            smem[OFF_TW + rrt*KSEL + k] = __expf(bl) * inv;
            ((int*)smem)[OFF_TI + rrt*KSEL + k] = bi;
        }
    }
    __syncthreads();

    // ---- epilogue: MLP mixture (overlays sPf/T24 regions) ----
    float* sH    = smem;                 // [16][52]
    float* sQ    = smem + 832;           // [16][500]
    float* sUd   = smem + OFF_UD;
    float* sTopW = smem + OFF_TW;
    int*   sTopI = (int*)smem + OFF_TI;

    const int gg = tid >> 4, lg = tid & 15;
    const int row = row0 + gg;
    const int rt_t = gg*2, rt_s = gg*2 + 1;
    const int uidx = is64 ? x32[4*row]     : x32[2*row];
    const int iidx = is64 ? x32[4*row + 2] : x32[2*row + 1];

    if (lg < DIMD) sUd[gg*12 + lg] = suid[uidx*DIMD + lg];
    __syncthreads();

    for (int t = lg; t < MDIM*DIMD; t += 16) {
        const int j = t / DIMD, e = t - j*DIMD;
        float q = 0.f;
        #pragma unroll
        for (int d = 0; d < DIMD; ++d) q += sUd[gg*12 + d] * mw2[j*(DIMD*DIMD) + d*DIMD + e];
        sQ[gg*500 + t] = q;
    }
    for (int mm = lg; mm < MDIM; mm += 16) {
        float v = 0.f;
        #pragma unroll
        for (int k = 0; k < KSEL; ++k)
            v += sTopW[rt_t*KSEL + k] * Cm[sTopI[rt_t*KSEL + k]*MDIM + mm];
        sH[gg*52 + mm] = v;
    }
    __syncthreads();

    float acc_e = 0.f, be = 0.f;
    if (lg < DIMD) {
        for (int m2 = 0; m2 < MDIM; ++m2) acc_e += sH[gg*52 + m2] * w2[m2*DIMD + lg];
        #pragma unroll
        for (int d = 0; d < DIMD; ++d) be += sUd[gg*12 + d] * mb2[d*DIMD + lg];
    }
    __syncthreads();

    for (int k = 0; k < KSEL; ++k) {
        const int   ik = sTopI[rt_s*KSEL + k];
        const float tw = sTopW[rt_s*KSEL + k];
        for (int j = lg; j < MDIM; j += 16) {
            float hh = mb1[j];
            const float* crow = Cm + ik*MDIM;
            for (int t2 = 0; t2 < MDIM; ++t2) hh += crow[t2] * mw1[t2*MDIM + j];
            #pragma unroll
            for (int d = 0; d < DIMD; ++d) hh += sUd[gg*12 + d] * mw1[(MDIM + d)*MDIM + j];
            sH[gg*52 + j] = fmaxf(hh, 0.f);
        }
        __syncthreads();
        if (lg < DIMD) {
            float se = be;
            for (int j = 0; j < MDIM; ++j) se += sH[gg*52 + j] * sQ[gg*500 + j*DIMD + lg];
            acc_e += tw * se;
        }
        __syncthreads();
    }

    float o = 0.f;
    if (lg < DIMD) o = acc_e * tiid[iidx*DIMD + lg];
    #pragma unroll
    for (int k = 8; k >= 1; k >>= 1) o += __shfl_xor(o, k, 16);
    if (lg == 0) out[row] = o;
}

extern "C" void kernel_launch(void* const* d_in, const int* in_sizes, int n_in,
                              void* d_out, int out_size, void* d_ws, size_t ws_size,
                              hipStream_t stream) {
    (void)in_sizes; (void)n_in; (void)out_size;
    const int*   x32  = (const int*)d_in[0];
    const float* gsrc = (const float*)d_in[1];
    const float* gtgt = (const float*)d_in[2];
    const float* suid = (const float*)d_in[3];
    const float* tuid = (const float*)d_in[4];
    const float* tiid = (const float*)d_in[5];
    const float* Cm   = (const float*)d_in[6];
    const float* w1   = (const float*)d_in[7];
    const float* w2   = (const float*)d_in[8];
    const float* mw1  = (const float*)d_in[9];
    const float* mb1  = (const float*)d_in[10];
    const float* mw2  = (const float*)d_in[11];
    const float* mb2  = (const float*)d_in[12];
    u32* C16 = (u32*)d_ws;

    if (ws_size >= 262144) {
        hipLaunchKernelGGL(cvtC, dim3(256), dim3(256), 0, stream, Cm, C16);
        hipLaunchKernelGGL(mf_fused<true>, dim3(BROWS/RPB), dim3(256), 0, stream,
                           x32, gsrc, gtgt, suid, tuid, tiid, Cm, w1, w2, mw1, mb1, mw2, mb2,
                           C16, (float*)d_out);
    } else {
        hipLaunchKernelGGL(mf_fused<false>, dim3(BROWS/RPB), dim3(256), 0, stream,
                           x32, gsrc, gtgt, suid, tuid, tiid, Cm, w1, w2, mw1, mb1, mw2, mb2,
                           C16, (float*)d_out);
    }
}

// Round 5
// 266.775 us; speedup vs baseline: 2.1422x; 1.0590x over previous
//
#include <hip/hip_runtime.h>
#include <hip/hip_bf16.h>

// MFBasedModel fused kernel, round 5: explicit software-pipelined u-stream
// (prefetch depth 4, statically-indexed rotation regs) + fragment-permuted C16
// planes (coalesced 1KB wave loads). Selection/recompute/finalize/epilogue
// identical to the passing round-4 kernel.

#define BROWS 16384
#define CNUM  2048
#define KSEL  8
#define DIMD  10
#define MDIM  50
#define RPB   16
#define RTPB  32
#define TAUI  0.1f
#define T24   24

// LDS word offsets
#define OFF_PF   0      // 1664 w : sPf [32][52] f32 (cols 50,51 zero)
#define OFF_T24  1664   // 768 w  : smashed top-12 x 2 halves per rt (uint)
#define OFF_T24L 2432   // 768 w  : exact l per entry
#define OFF_TS   3200   // 64 w   : exp-sum partials [rt][half]
#define OFF_TW   8832   // 256 w
#define OFF_TI   9088   // 256 w (int)
#define OFF_UD   9344   // 192 w : sUd [16][12]
#define SMEM_W   9536
// epilogue overlay: sH = smem+0 (832 w), sQ = smem+832 (8000 w)

typedef float    f32x4 __attribute__((ext_vector_type(4)));
typedef _Float16 half8 __attribute__((ext_vector_type(8)));
typedef float    flt2  __attribute__((ext_vector_type(2)));
typedef unsigned int u32;

__device__ __forceinline__ u32 pkrtz(float a, float b) {
    auto h = __builtin_amdgcn_cvt_pkrtz(a, b);
    union { decltype(h) v; u32 u; } c; c.v = h; return c.u;
}
__device__ __forceinline__ float gnoise(float u) {
    return -__logf(-__logf(u + 1e-20f) + 1e-20f);
}

// ---- pre-kernel: C f32 [2048][50] -> fragment-permuted fp16 planes ----
// layout: word[((Tg*2 + plane)*64 + lane)*4 + w], Tg=cand-tile (16 cands),
// cand = Tg*16 + (lane&15), k-halfpair index kk = plane*16 + (lane>>4)*4 + w.
__global__ void cvtC(const float* __restrict__ Cm, u32* __restrict__ C16) {
    const int j = blockIdx.x * 256 + threadIdx.x;   // 131072 words
    const int w = j & 3, l = (j >> 2) & 63, pl = (j >> 8) & 1, Tg = j >> 9;
    const int cand = Tg * 16 + (l & 15);
    const int kk = pl * 16 + ((l >> 4) << 2) + w;
    const int k = 2 * kk;
    const float a = (k < MDIM)     ? Cm[cand*MDIM + k]     : 0.f;
    const float b = (k + 1 < MDIM) ? Cm[cand*MDIM + k + 1] : 0.f;
    C16[j] = pkrtz(a, b);
}

template<bool PRE>
__global__ __launch_bounds__(256, 4)
void mf_fused(const int* __restrict__ x32,
              const float* __restrict__ gsrc,
              const float* __restrict__ gtgt,
              const float* __restrict__ suid,
              const float* __restrict__ tuid,
              const float* __restrict__ tiid,
              const float* __restrict__ Cm,
              const float* __restrict__ w1,
              const float* __restrict__ w2,
              const float* __restrict__ mw1,
              const float* __restrict__ mb1,
              const float* __restrict__ mw2,
              const float* __restrict__ mb2,
              const u32* __restrict__ C16,
              float* __restrict__ out)
{
    __shared__ __align__(16) float smem[SMEM_W];
    __shared__ int sFlag;
    float* sPf  = smem + OFF_PF;
    u32*   T24u = (u32*)(smem + OFF_T24);
    float* T24l = smem + OFF_T24L;

    const int tid  = threadIdx.x;
    const int row0 = blockIdx.x * RPB;

    // ---- x dtype detect ----
    if (tid == 0) sFlag = 1;
    __syncthreads();
    if (tid < 128) { if (x32[2*tid+1] != 0) atomicAnd(&sFlag, 0); }
    __syncthreads();
    const int is64 = sFlag;

    // ---- sPf = emb @ w1 (f32), zero-padded to 52 cols ----
    for (int t = tid; t < RTPB*52; t += 256) {
        const int rt = t / 52, mm = t - rt*52;
        float v = 0.f;
        if (mm < MDIM) {
            const int r = row0 + (rt >> 1);
            const int uidx = is64 ? x32[4*r] : x32[2*r];
            const float* tab = (rt & 1) ? suid : tuid;
            #pragma unroll
            for (int d = 0; d < DIMD; ++d) v += tab[uidx*DIMD + d] * w1[d*MDIM + mm];
        }
        sPf[t] = v;
    }
    __syncthreads();

    // ---- lane decomposition: wave wv -> rt-group g=wv&1, cand-half h=wv>>1 ----
    const int lane = tid & 63, wv = tid >> 6;
    const int lr = lane & 15, lk = lane >> 4;
    const int g = wv & 1, h = wv >> 1;
    const int rt = g*16 + lr;
    const float* up = ((lr & 1) ? gsrc : gtgt) + (size_t)(row0 + g*8 + (lr >> 1)) * CNUM;

    // B-fragments: P16[rt][k] built in regs from sPf
    half8 b0, b1;
    {
        union { u32 u[4]; half8 v; } c0, c1;
        #pragma unroll
        for (int jj = 0; jj < 4; ++jj) {
            const int k0 = lk*8 + jj*2;
            c0.u[jj] = pkrtz(sPf[rt*52 + k0], sPf[rt*52 + k0 + 1]);
            const int k1 = 32 + lk*8 + jj*2;
            const float e0 = (k1     < 52) ? sPf[rt*52 + k1]     : 0.f;
            const float e1 = (k1 + 1 < 52) ? sPf[rt*52 + k1 + 1] : 0.f;
            c1.u[jj] = pkrtz(e0, e1);
        }
        b0 = c0.v; b1 = c1.v;
    }

    float ts = 0.f;
    float q0=-3.4e38f,q1=-3.4e38f,q2=-3.4e38f,q3=-3.4e38f,
          q4=-3.4e38f,q5=-3.4e38f,q6=-3.4e38f,q7=-3.4e38f;

    // selection body (shared by both paths)
    auto select4 = [&](const f32x4& acc, const f32x4& u4, int cg) {
        #pragma unroll
        for (int r4 = 0; r4 < 4; ++r4) {
            const float l = (acc[r4] + gnoise(u4[r4])) * TAUI;
            ts += __expf(l);
            const float xs = __uint_as_float(
                (__float_as_uint(l) & 0xFFFFF800u) | (u32)(cg + r4));
            q0 = fmaxf(q0, fminf(q1, xs));
            q1 = fmaxf(q1, fminf(q2, xs));
            q2 = fmaxf(q2, fminf(q3, xs));
            q3 = fmaxf(q3, fminf(q4, xs));
            q4 = fmaxf(q4, fminf(q5, xs));
            q5 = fmaxf(q5, fminf(q6, xs));
            q6 = fmaxf(q6, fminf(q7, xs));
            q7 = fmaxf(q7, xs);
        }
    };

    if (PRE) {
        // ---- software-pipelined main loop: u depth-4, C depth-2 ----
        auto uaddr = [&](int t) -> const float* {
            return up + (((t >> 2) << 7) + h*64 + ((t & 3) << 4) + lk*4);
        };
        auto caddr = [&](int t) -> const u32* {
            const int Tg = ((t >> 2) << 3) + (h << 2) + (t & 3);
            return C16 + ((size_t)(Tg * 2) * 64 + lane) * 4;
        };
        f32x4 ub0 = *(const f32x4*)uaddr(0);
        f32x4 ub1 = *(const f32x4*)uaddr(1);
        f32x4 ub2 = *(const f32x4*)uaddr(2);
        f32x4 ub3 = *(const f32x4*)uaddr(3);
        const u32* ca0 = caddr(0);
        const u32* ca1 = caddr(1);
        half8 a00 = *(const half8*)ca0;
        half8 a10 = *(const half8*)(ca0 + 256);
        half8 a01 = *(const half8*)ca1;
        half8 a11 = *(const half8*)(ca1 + 256);

        for (int tt = 0; tt < 64; tt += 4) {
            #pragma unroll
            for (int p = 0; p < 4; ++p) {
                const int t = tt + p;
                f32x4 u4;
                if      (p == 0) u4 = ub0;
                else if (p == 1) u4 = ub1;
                else if (p == 2) u4 = ub2;
                else             u4 = ub3;
                half8 a0, a1;
                if ((p & 1) == 0) { a0 = a00; a1 = a10; }
                else              { a0 = a01; a1 = a11; }
                // prefetch u for t+4
                {
                    const int tu = (t + 4) & 63;
                    const f32x4 un = *(const f32x4*)uaddr(tu);
                    if      (p == 0) ub0 = un;
                    else if (p == 1) ub1 = un;
                    else if (p == 2) ub2 = un;
                    else             ub3 = un;
                }
                // prefetch C for t+2
                {
                    const int tc = (t + 2) & 63;
                    const u32* ca = caddr(tc);
                    const half8 an0 = *(const half8*)ca;
                    const half8 an1 = *(const half8*)(ca + 256);
                    if ((p & 1) == 0) { a00 = an0; a10 = an1; }
                    else              { a01 = an0; a11 = an1; }
                }
                // compute
                const int cb = ((t >> 2) << 7) + h*64 + ((t & 3) << 4);
                f32x4 acc = {0.f, 0.f, 0.f, 0.f};
                acc = __builtin_amdgcn_mfma_f32_16x16x32_f16(a0, b0, acc, 0, 0, 0);
                acc = __builtin_amdgcn_mfma_f32_16x16x32_f16(a1, b1, acc, 0, 0, 0);
                select4(acc, u4, cb + lk*4);
            }
        }
    } else {
        // fallback: unpipelined, converts C from f32 in-flight
        for (int t = 0; t < 64; ++t) {
            const int cb = ((t >> 2) << 7) + h*64 + ((t & 3) << 4);
            const float* cr = Cm + (size_t)(cb + lr)*MDIM;
            union { u32 u[4]; half8 v; } c0, c1;
            #pragma unroll
            for (int jj = 0; jj < 4; ++jj) {
                const int k0 = lk*8 + jj*2;
                c0.u[jj] = pkrtz(cr[k0], cr[k0+1]);
                const int k1 = 32 + lk*8 + jj*2;
                const float e0 = (k1     < MDIM) ? cr[k1]   : 0.f;
                const float e1 = (k1 + 1 < MDIM) ? cr[k1+1] : 0.f;
                c1.u[jj] = pkrtz(e0, e1);
            }
            f32x4 acc = {0.f, 0.f, 0.f, 0.f};
            acc = __builtin_amdgcn_mfma_f32_16x16x32_f16(c0.v, b0, acc, 0, 0, 0);
            acc = __builtin_amdgcn_mfma_f32_16x16x32_f16(c1.v, b1, acc, 0, 0, 0);
            const f32x4 u4 = *(const f32x4*)(up + cb + lk*4);
            select4(acc, u4, cb + lk*4);
        }
    }

    // ---- merge over lk lanes (xor 16/32): exp-sum + top-12 tournament ----
    {
        float tss = ts;
        tss += __shfl_xor(tss, 16); tss += __shfl_xor(tss, 32);
        if (lk == 0) smem[OFF_TS + rt*2 + h] = tss;
        #pragma unroll
        for (int k = 0; k < 12; ++k) {
            float gm = fmaxf(q7, __shfl_xor(q7, 16));
            gm = fmaxf(gm, __shfl_xor(gm, 32));
            if (q7 == gm) {
                T24u[rt*T24 + h*12 + k] = __float_as_uint(q7);
                q7=q6; q6=q5; q5=q4; q4=q3; q3=q2; q2=q1; q1=q0; q0=-3.4e38f;
            }
        }
    }
    __syncthreads();

    // ---- exact f32 recompute of the 24 candidates per rt ----
    for (int e = tid; e < RTPB*T24; e += 256) {
        const int ert = e / T24;
        const int idx = (int)(T24u[e] & 2047u);
        const float* pf = sPf + ert*52;
        const float* cr = Cm + idx*MDIM;
        float s = 0.f;
        #pragma unroll
        for (int k2 = 0; k2 < 25; ++k2) {
            flt2 c = *(const flt2*)(cr + k2*2);
            s += pf[2*k2] * c.x + pf[2*k2+1] * c.y;
        }
        const int r = row0 + (ert >> 1);
        const float u = ((ert & 1) ? gsrc : gtgt)[(size_t)r*CNUM + idx];
        T24l[e] = (s + gnoise(u)) * TAUI;
    }
    __syncthreads();

    // ---- exact top-8 of 24 (tiebreak lower index), weights ----
    if (tid < RTPB) {
        const int rrt = tid;
        const float inv = 1.0f / (smem[OFF_TS + rrt*2] + smem[OFF_TS + rrt*2 + 1]);
        float lv[T24]; int iv[T24];
        #pragma unroll
        for (int j = 0; j < T24; ++j) {
            lv[j] = T24l[rrt*T24 + j];
            iv[j] = (int)(T24u[rrt*T24 + j] & 2047u);
        }
        u32 used = 0;
        #pragma unroll
        for (int k = 0; k < KSEL; ++k) {
            float bl = -3.4e38f; int bi = 1 << 30; int bj = 0;
            #pragma unroll
            for (int j = 0; j < T24; ++j) {
                const bool ok = !((used >> j) & 1);
                if (ok && (lv[j] > bl || (lv[j] == bl && iv[j] < bi))) { bl = lv[j]; bi = iv[j]; bj = j; }
            }
            used |= 1u << bj;
            smem[OFF_TW + rrt*KSEL + k] = __expf(bl) * inv;
            ((int*)smem)[OFF_TI + rrt*KSEL + k] = bi;
        }
    }
    __syncthreads();

    // ---- epilogue: MLP mixture (overlays sPf/T24 regions) ----
    float* sH    = smem;                 // [16][52]
    float* sQ    = smem + 832;           // [16][500]
    float* sUd   = smem + OFF_UD;
    float* sTopW = smem + OFF_TW;
    int*   sTopI = (int*)smem + OFF_TI;

    const int gg = tid >> 4, lg = tid & 15;
    const int row = row0 + gg;
    const int rt_t = gg*2, rt_s = gg*2 + 1;
    const int uidx = is64 ? x32[4*row]     : x32[2*row];
    const int iidx = is64 ? x32[4*row + 2] : x32[2*row + 1];

    if (lg < DIMD) sUd[gg*12 + lg] = suid[uidx*DIMD + lg];
    __syncthreads();

    for (int t = lg; t < MDIM*DIMD; t += 16) {
        const int j = t / DIMD, e = t - j*DIMD;
        float q = 0.f;
        #pragma unroll
        for (int d = 0; d < DIMD; ++d) q += sUd[gg*12 + d] * mw2[j*(DIMD*DIMD) + d*DIMD + e];
        sQ[gg*500 + t] = q;
    }
    for (int mm = lg; mm < MDIM; mm += 16) {
        float v = 0.f;
        #pragma unroll
        for (int k = 0; k < KSEL; ++k)
            v += sTopW[rt_t*KSEL + k] * Cm[sTopI[rt_t*KSEL + k]*MDIM + mm];
        sH[gg*52 + mm] = v;
    }
    __syncthreads();

    float acc_e = 0.f, be = 0.f;
    if (lg < DIMD) {
        for (int m2 = 0; m2 < MDIM; ++m2) acc_e += sH[gg*52 + m2] * w2[m2*DIMD + lg];
        #pragma unroll
        for (int d = 0; d < DIMD; ++d) be += sUd[gg*12 + d] * mb2[d*DIMD + lg];
    }
    __syncthreads();

    for (int k = 0; k < KSEL; ++k) {
        const int   ik = sTopI[rt_s*KSEL + k];
        const float tw = sTopW[rt_s*KSEL + k];
        for (int j = lg; j < MDIM; j += 16) {
            float hh = mb1[j];
            const float* crow = Cm + ik*MDIM;
            for (int t2 = 0; t2 < MDIM; ++t2) hh += crow[t2] * mw1[t2*MDIM + j];
            #pragma unroll
            for (int d = 0; d < DIMD; ++d) hh += sUd[gg*12 + d] * mw1[(MDIM + d)*MDIM + j];
            sH[gg*52 + j] = fmaxf(hh, 0.f);
        }
        __syncthreads();
        if (lg < DIMD) {
            float se = be;
            for (int j = 0; j < MDIM; ++j) se += sH[gg*52 + j] * sQ[gg*500 + j*DIMD + lg];
            acc_e += tw * se;
        }
        __syncthreads();
    }

    float o = 0.f;
    if (lg < DIMD) o = acc_e * tiid[iidx*DIMD + lg];
    #pragma unroll
    for (int k = 8; k >= 1; k >>= 1) o += __shfl_xor(o, k, 16);
    if (lg == 0) out[row] = o;
}

extern "C" void kernel_launch(void* const* d_in, const int* in_sizes, int n_in,
                              void* d_out, int out_size, void* d_ws, size_t ws_size,
                              hipStream_t stream) {
    (void)in_sizes; (void)n_in; (void)out_size;
    const int*   x32  = (const int*)d_in[0];
    const float* gsrc = (const float*)d_in[1];
    const float* gtgt = (const float*)d_in[2];
    const float* suid = (const float*)d_in[3];
    const float* tuid = (const float*)d_in[4];
    const float* tiid = (const float*)d_in[5];
    const float* Cm   = (const float*)d_in[6];
    const float* w1   = (const float*)d_in[7];
    const float* w2   = (const float*)d_in[8];
    const float* mw1  = (const float*)d_in[9];
    const float* mb1  = (const float*)d_in[10];
    const float* mw2  = (const float*)d_in[11];
    const float* mb2  = (const float*)d_in[12];
    u32* C16 = (u32*)d_ws;

    if (ws_size >= 524288) {
        hipLaunchKernelGGL(cvtC, dim3(512), dim3(256), 0, stream, Cm, C16);
        hipLaunchKernelGGL(mf_fused<true>, dim3(BROWS/RPB), dim3(256), 0, stream,
                           x32, gsrc, gtgt, suid, tuid, tiid, Cm, w1, w2, mw1, mb1, mw2, mb2,
                           C16, (float*)d_out);
    } else {
        hipLaunchKernelGGL(mf_fused<false>, dim3(BROWS/RPB), dim3(256), 0, stream,
                           x32, gsrc, gtgt, suid, tuid, tiid, Cm, w1, w2, mw1, mb1, mw2, mb2,
                           C16, (float*)d_out);
    }
}